// Round 1
// baseline (1216.987 us; speedup 1.0000x reference)
//
#include <hip/hip_runtime.h>

#define BATCH 8
#define CH 128
#define HH 128
#define WW 128
#define HWSZ 16384
#define NHEADS 8
#define DHEAD 2048
#define NSPLIT 8

// ---------------- Kernel 1: fused depthwise 9x9 conv for q,k,v ----------------
// grid: B*C*16 blocks; each block one 32x32 output tile for one (b,c).
// Each thread computes 4 consecutive-x outputs for all three convs.
__global__ __launch_bounds__(256) void dwconv_qkv_kernel(
    const float* __restrict__ x,
    const float* __restrict__ wq, const float* __restrict__ bq,
    const float* __restrict__ wk, const float* __restrict__ bk,
    const float* __restrict__ wv, const float* __restrict__ bv,
    float* __restrict__ Q, float* __restrict__ K, float* __restrict__ V)
{
    const int blk  = blockIdx.x;
    const int tile = blk & 15;
    const int bc   = blk >> 4;             // b*128 + c
    const int c    = bc & (CH - 1);
    const int ty0  = (tile >> 2) << 5;
    const int tx0  = (tile & 3) << 5;

    __shared__ float sm[40][40];           // 32x32 tile + 4-halo
    const float* xp = x + (size_t)bc * HWSZ;
    const int tid = threadIdx.x;
    for (int i = tid; i < 1600; i += 256) {
        int r = i / 40;
        int col = i - r * 40;
        int gy = ty0 + r - 4;
        int gx = tx0 + col - 4;
        float v = 0.f;
        if ((unsigned)gy < HH && (unsigned)gx < WW) v = xp[gy * WW + gx];
        sm[r][col] = v;
    }
    __syncthreads();

    const float* wqp = wq + c * 81;        // uniform across block -> s_load
    const float* wkp = wk + c * 81;
    const float* wvp = wv + c * 81;

    const int oy = tid >> 3;               // 0..31
    const int ox = (tid & 7) << 2;         // 0,4,...,28

    float accq[4], acck[4], accv[4];
    const float bqv = bq[c], bkv = bk[c], bvv = bv[c];
    #pragma unroll
    for (int j = 0; j < 4; ++j) { accq[j] = bqv; acck[j] = bkv; accv[j] = bvv; }

    for (int dy = 0; dy < 9; ++dy) {
        const float4* rp = (const float4*)&sm[oy + dy][ox];
        const float4 v0 = rp[0], v1 = rp[1], v2 = rp[2];
        const float vals[12] = {v0.x, v0.y, v0.z, v0.w, v1.x, v1.y, v1.z, v1.w,
                                v2.x, v2.y, v2.z, v2.w};
        #pragma unroll
        for (int dx = 0; dx < 9; ++dx) {
            const float wqv = wqp[dy * 9 + dx];
            const float wkv = wkp[dy * 9 + dx];
            const float wvv = wvp[dy * 9 + dx];
            #pragma unroll
            for (int j = 0; j < 4; ++j) {
                const float xv = vals[dx + j];
                accq[j] = fmaf(wqv, xv, accq[j]);
                acck[j] = fmaf(wkv, xv, acck[j]);
                accv[j] = fmaf(wvv, xv, accv[j]);
            }
        }
    }
    const size_t o = (size_t)bc * HWSZ + (size_t)(ty0 + oy) * WW + tx0 + ox;
    *(float4*)&Q[o] = make_float4(accq[0], accq[1], accq[2], accq[3]);
    *(float4*)&K[o] = make_float4(acck[0], acck[1], acck[2], acck[3]);
    *(float4*)&V[o] = make_float4(accv[0], accv[1], accv[2], accv[3]);
}

// ---------------- Kernel 2: S[bh] += Q_h K_h^T over a t-chunk (split-K, atomics)
// grid: 64*(NSPLIT) blocks. Each block: full 128x128 Gram partial over t-chunk.
__global__ __launch_bounds__(256) void qk_kernel(
    const float* __restrict__ Q, const float* __restrict__ K, float* __restrict__ S)
{
    const int blk   = blockIdx.x;
    const int split = blk & (NSPLIT - 1);
    const int bh    = blk / NSPLIT;        // b*8 + hd
    const int b     = bh >> 3;
    const int hd    = bh & 7;
    const int TCH   = DHEAD / NSPLIT;      // 256
    const int t0    = split * TCH;

    __shared__ float qs[8][128];           // [tt][c]
    __shared__ float ks[8][128];           // [tt][e]

    const int tid = threadIdx.x;
    const int c0  = (tid & 15) << 3;
    const int e0  = (tid >> 4) << 3;
    const int cc  = tid & 127;
    const int th  = (tid >> 7) << 2;       // 0 or 4

    float acc[8][8];
    #pragma unroll
    for (int i = 0; i < 8; ++i)
        #pragma unroll
        for (int j = 0; j < 8; ++j) acc[i][j] = 0.f;

    const float* Qb = Q + (size_t)b * CH * HWSZ + hd * DHEAD;
    const float* Kb = K + (size_t)b * CH * HWSZ + hd * DHEAD;

    #pragma unroll 1
    for (int t = t0; t < t0 + TCH; t += 8) {
        const float4 qv = *(const float4*)&Qb[cc * HWSZ + t + th];
        const float4 kv = *(const float4*)&Kb[cc * HWSZ + t + th];
        __syncthreads();
        qs[th + 0][cc] = qv.x; qs[th + 1][cc] = qv.y;
        qs[th + 2][cc] = qv.z; qs[th + 3][cc] = qv.w;
        ks[th + 0][cc] = kv.x; ks[th + 1][cc] = kv.y;
        ks[th + 2][cc] = kv.z; ks[th + 3][cc] = kv.w;
        __syncthreads();
        #pragma unroll
        for (int tt = 0; tt < 8; ++tt) {
            const float4 qa  = *(const float4*)&qs[tt][c0];
            const float4 qb4 = *(const float4*)&qs[tt][c0 + 4];
            const float4 ka  = *(const float4*)&ks[tt][e0];
            const float4 kb4 = *(const float4*)&ks[tt][e0 + 4];
            const float qr[8] = {qa.x, qa.y, qa.z, qa.w, qb4.x, qb4.y, qb4.z, qb4.w};
            const float kr[8] = {ka.x, ka.y, ka.z, ka.w, kb4.x, kb4.y, kb4.z, kb4.w};
            #pragma unroll
            for (int i = 0; i < 8; ++i)
                #pragma unroll
                for (int j = 0; j < 8; ++j)
                    acc[i][j] = fmaf(qr[i], kr[j], acc[i][j]);
        }
    }
    float* Sp = S + (size_t)bh * CH * CH;
    #pragma unroll
    for (int i = 0; i < 8; ++i)
        #pragma unroll
        for (int j = 0; j < 8; ++j)
            atomicAdd(&Sp[(c0 + i) * CH + e0 + j], acc[i][j]);
}

// ---------------- Kernel 3: row softmax of S (scale 1/128), in place ----------
// 8192 rows of length 128; one wave per row.
__global__ __launch_bounds__(256) void softmax_kernel(float* __restrict__ S)
{
    const int row  = blockIdx.x * 4 + (threadIdx.x >> 6);
    const int lane = threadIdx.x & 63;
    float* Sp = S + (size_t)row * CH;
    const float v0 = Sp[lane] * 0.0078125f;
    const float v1 = Sp[lane + 64] * 0.0078125f;
    float m = fmaxf(v0, v1);
    #pragma unroll
    for (int off = 32; off > 0; off >>= 1) m = fmaxf(m, __shfl_down(m, off));
    m = __shfl(m, 0);
    const float e0 = __expf(v0 - m);
    const float e1 = __expf(v1 - m);
    float s = e0 + e1;
    #pragma unroll
    for (int off = 32; off > 0; off >>= 1) s += __shfl_down(s, off);
    s = __shfl(s, 0);
    const float inv = 1.f / s;
    Sp[lane]      = e0 * inv;
    Sp[lane + 64] = e1 * inv;
}

// ---------------- Kernel 4: A_h = P V_h  (128x2048 = 128x128 * 128x2048) ------
// grid: 64 bh * 16 t-tiles of 128.
__global__ __launch_bounds__(256) void pv_kernel(
    const float* __restrict__ P, const float* __restrict__ V, float* __restrict__ A)
{
    const int blk = blockIdx.x;
    const int tt0 = (blk & 15) << 7;
    const int bh  = blk >> 4;
    const int b   = bh >> 3;
    const int hd  = bh & 7;

    __shared__ float ps[8][128];           // [ee][c]
    __shared__ float vs[8][128];           // [ee][tl]

    const int tid = threadIdx.x;
    const int c0  = (tid & 15) << 3;
    const int tl0 = (tid >> 4) << 3;

    const int pcc = tid & 127;
    const int pth = (tid >> 7) << 2;       // 0 or 4
    const int vr  = tid >> 5;              // 0..7
    const int vc  = (tid & 31) << 2;       // 0..124

    float acc[8][8];
    #pragma unroll
    for (int i = 0; i < 8; ++i)
        #pragma unroll
        for (int j = 0; j < 8; ++j) acc[i][j] = 0.f;

    const float* Pp = P + (size_t)bh * CH * CH;
    const float* Vp = V + (size_t)b * CH * HWSZ + hd * DHEAD + tt0;

    #pragma unroll 1
    for (int e0i = 0; e0i < CH; e0i += 8) {
        const float4 pv4 = *(const float4*)&Pp[pcc * CH + e0i + pth];
        const float4 vv4 = *(const float4*)&Vp[(e0i + vr) * HWSZ + vc];
        __syncthreads();
        ps[pth + 0][pcc] = pv4.x; ps[pth + 1][pcc] = pv4.y;
        ps[pth + 2][pcc] = pv4.z; ps[pth + 3][pcc] = pv4.w;
        *(float4*)&vs[vr][vc] = vv4;
        __syncthreads();
        #pragma unroll
        for (int ee = 0; ee < 8; ++ee) {
            const float4 pa = *(const float4*)&ps[ee][c0];
            const float4 pb = *(const float4*)&ps[ee][c0 + 4];
            const float4 va = *(const float4*)&vs[ee][tl0];
            const float4 vb = *(const float4*)&vs[ee][tl0 + 4];
            const float pr[8] = {pa.x, pa.y, pa.z, pa.w, pb.x, pb.y, pb.z, pb.w};
            const float vr8[8] = {va.x, va.y, va.z, va.w, vb.x, vb.y, vb.z, vb.w};
            #pragma unroll
            for (int i = 0; i < 8; ++i)
                #pragma unroll
                for (int j = 0; j < 8; ++j)
                    acc[i][j] = fmaf(pr[i], vr8[j], acc[i][j]);
        }
    }
    float* Ap = A + (size_t)b * CH * HWSZ + hd * DHEAD + tt0;
    #pragma unroll
    for (int i = 0; i < 8; ++i) {
        *(float4*)&Ap[(c0 + i) * HWSZ + tl0]     = make_float4(acc[i][0], acc[i][1], acc[i][2], acc[i][3]);
        *(float4*)&Ap[(c0 + i) * HWSZ + tl0 + 4] = make_float4(acc[i][4], acc[i][5], acc[i][6], acc[i][7]);
    }
}

// ---------------- Kernel 5: 3x3 dense conv (+bias) -----------------------------
// grid: B * H * 2; block computes out[64 co][row y][128 x] for one b.
// Thread: 8 co x 4 x register tile. K-loop over ci in chunks of 8.
__global__ __launch_bounds__(256) void conv3x3_kernel(
    const float* __restrict__ A, const float* __restrict__ wo,
    const float* __restrict__ bo, float* __restrict__ out)
{
    const int blk  = blockIdx.x;
    const int half = blk & 1;
    const int y    = (blk >> 1) & (HH - 1);
    const int b    = blk >> 8;

    __shared__ float as[8][3][132];        // [ci][dy][x+1], x in -1..129
    __shared__ float ws[8][9][64];         // [ci][tap][co_local]

    const int tid     = threadIdx.x;
    const int x0      = (tid & 31) << 2;   // 0..124
    const int tg      = tid >> 5;          // 0..7
    const int co_base = half * 64;
    const int co0     = co_base + tg * 8;

    float acc[8][4];
    #pragma unroll
    for (int i = 0; i < 8; ++i) {
        const float bb = bo[co0 + i];
        #pragma unroll
        for (int j = 0; j < 4; ++j) acc[i][j] = bb;
    }

    const float* Ab = A + (size_t)b * CH * HWSZ;

    #pragma unroll 1
    for (int ci0 = 0; ci0 < CH; ci0 += 8) {
        __syncthreads();
        // stage activations: 8 ci x 3 rows x 130 x (with zero pad)
        for (int idx = tid; idx < 3120; idx += 256) {
            int ci  = idx / 390;
            int rem = idx - ci * 390;
            int dy  = rem / 130;
            int xi  = rem - dy * 130 - 1;  // -1..128
            int gy  = y + dy - 1;
            float v = 0.f;
            if ((unsigned)gy < HH && (unsigned)xi < WW)
                v = Ab[(ci0 + ci) * HWSZ + gy * WW + xi];
            as[ci][dy][xi + 1] = v;
        }
        // stage weights: 64 co x (8 ci * 9 taps)
        for (int idx = tid; idx < 4608; idx += 256) {
            int co = idx / 72;
            int j  = idx - co * 72;
            int ci = j / 9;
            int tap = j - ci * 9;
            ws[ci][tap][co] = wo[(size_t)(co_base + co) * (CH * 9) + ci0 * 9 + j];
        }
        __syncthreads();

        for (int ci = 0; ci < 8; ++ci) {
            #pragma unroll
            for (int dy = 0; dy < 3; ++dy) {
                const float4 a4 = *(const float4*)&as[ci][dy][x0];
                const float2 a2 = *(const float2*)&as[ci][dy][x0 + 4];
                const float av[6] = {a4.x, a4.y, a4.z, a4.w, a2.x, a2.y};
                #pragma unroll
                for (int dx = 0; dx < 3; ++dx) {
                    const float4 w4a = *(const float4*)&ws[ci][dy * 3 + dx][tg * 8];
                    const float4 w4b = *(const float4*)&ws[ci][dy * 3 + dx][tg * 8 + 4];
                    const float wv8[8] = {w4a.x, w4a.y, w4a.z, w4a.w,
                                          w4b.x, w4b.y, w4b.z, w4b.w};
                    #pragma unroll
                    for (int i = 0; i < 8; ++i)
                        #pragma unroll
                        for (int j = 0; j < 4; ++j)
                            acc[i][j] = fmaf(wv8[i], av[dx + j], acc[i][j]);
                }
            }
        }
    }
    float* op = out + (size_t)b * CH * HWSZ + (size_t)y * WW + x0;
    #pragma unroll
    for (int i = 0; i < 8; ++i)
        *(float4*)&op[(size_t)(co0 + i) * HWSZ] =
            make_float4(acc[i][0], acc[i][1], acc[i][2], acc[i][3]);
}

extern "C" void kernel_launch(void* const* d_in, const int* in_sizes, int n_in,
                              void* d_out, int out_size, void* d_ws, size_t ws_size,
                              hipStream_t stream)
{
    const float* x  = (const float*)d_in[0];
    const float* wq = (const float*)d_in[1];
    const float* bq = (const float*)d_in[2];
    const float* wk = (const float*)d_in[3];
    const float* bk = (const float*)d_in[4];
    const float* wv = (const float*)d_in[5];
    const float* bv = (const float*)d_in[6];
    const float* wo = (const float*)d_in[7];
    const float* bo = (const float*)d_in[8];

    // Q lives in d_out (consumed before the final conv overwrites d_out).
    float* Q  = (float*)d_out;
    float* ws = (float*)d_ws;
    float* K  = ws;
    float* V  = ws + (size_t)16777216;
    float* A  = ws + (size_t)2 * 16777216;
    float* S  = ws + (size_t)3 * 16777216;   // 64 * 128 * 128 floats

    dwconv_qkv_kernel<<<BATCH * CH * 16, 256, 0, stream>>>(x, wq, bq, wk, bk, wv, bv, Q, K, V);
    hipMemsetAsync(S, 0, (size_t)64 * CH * CH * sizeof(float), stream);
    qk_kernel<<<64 * NSPLIT, 256, 0, stream>>>(Q, K, S);
    softmax_kernel<<<2048, 256, 0, stream>>>(S);
    pv_kernel<<<64 * 16, 256, 0, stream>>>(S, V, A);
    conv3x3_kernel<<<BATCH * HH * 2, 256, 0, stream>>>(A, wo, bo, (float*)d_out);
}

// Round 3
// 628.949 us; speedup vs baseline: 1.9350x; 1.9350x over previous
//
#include <hip/hip_runtime.h>

#define BATCH 8
#define CH 128
#define HH 128
#define WW 128
#define HWSZ 16384
#define NHEADS 8
#define DHEAD 2048
#define NSPLIT 8

typedef short bf16x8 __attribute__((ext_vector_type(8)));
typedef float f32x4 __attribute__((ext_vector_type(4)));

static __device__ inline unsigned short f2bf(float f) {
    unsigned u = __builtin_bit_cast(unsigned, f);
    u += 0x7fff + ((u >> 16) & 1);          // round-to-nearest-even
    return (unsigned short)(u >> 16);
}

// ---------------- Kernel 1: fused depthwise 9x9 conv for q,k,v ----------------
__global__ __launch_bounds__(256) void dwconv_qkv_kernel(
    const float* __restrict__ x,
    const float* __restrict__ wq, const float* __restrict__ bq,
    const float* __restrict__ wk, const float* __restrict__ bk,
    const float* __restrict__ wv, const float* __restrict__ bv,
    float* __restrict__ Q, float* __restrict__ K, float* __restrict__ V)
{
    const int blk  = blockIdx.x;
    const int tile = blk & 15;
    const int bc   = blk >> 4;             // b*128 + c
    const int c    = bc & (CH - 1);
    const int ty0  = (tile >> 2) << 5;
    const int tx0  = (tile & 3) << 5;

    __shared__ float sm[40][40];           // 32x32 tile + 4-halo
    const float* xp = x + (size_t)bc * HWSZ;
    const int tid = threadIdx.x;
    for (int i = tid; i < 1600; i += 256) {
        int r = i / 40;
        int col = i - r * 40;
        int gy = ty0 + r - 4;
        int gx = tx0 + col - 4;
        float v = 0.f;
        if ((unsigned)gy < HH && (unsigned)gx < WW) v = xp[gy * WW + gx];
        sm[r][col] = v;
    }
    __syncthreads();

    const float* wqp = wq + c * 81;
    const float* wkp = wk + c * 81;
    const float* wvp = wv + c * 81;

    const int oy = tid >> 3;               // 0..31
    const int ox = (tid & 7) << 2;         // 0,4,...,28

    float accq[4], acck[4], accv[4];
    const float bqv = bq[c], bkv = bk[c], bvv = bv[c];
    #pragma unroll
    for (int j = 0; j < 4; ++j) { accq[j] = bqv; acck[j] = bkv; accv[j] = bvv; }

    for (int dy = 0; dy < 9; ++dy) {
        const float4* rp = (const float4*)&sm[oy + dy][ox];
        const float4 v0 = rp[0], v1 = rp[1], v2 = rp[2];
        const float vals[12] = {v0.x, v0.y, v0.z, v0.w, v1.x, v1.y, v1.z, v1.w,
                                v2.x, v2.y, v2.z, v2.w};
        #pragma unroll
        for (int dx = 0; dx < 9; ++dx) {
            const float wqv = wqp[dy * 9 + dx];
            const float wkv = wkp[dy * 9 + dx];
            const float wvv = wvp[dy * 9 + dx];
            #pragma unroll
            for (int j = 0; j < 4; ++j) {
                const float xv = vals[dx + j];
                accq[j] = fmaf(wqv, xv, accq[j]);
                acck[j] = fmaf(wkv, xv, acck[j]);
                accv[j] = fmaf(wvv, xv, accv[j]);
            }
        }
    }
    const size_t o = (size_t)bc * HWSZ + (size_t)(ty0 + oy) * WW + tx0 + ox;
    *(float4*)&Q[o] = make_float4(accq[0], accq[1], accq[2], accq[3]);
    *(float4*)&K[o] = make_float4(acck[0], acck[1], acck[2], acck[3]);
    *(float4*)&V[o] = make_float4(accv[0], accv[1], accv[2], accv[3]);
}

// ---------------- Kernel 2: S[bh] += Q_h K_h^T (split-K, atomics) -------------
__global__ __launch_bounds__(256) void qk_kernel(
    const float* __restrict__ Q, const float* __restrict__ K, float* __restrict__ S)
{
    const int blk   = blockIdx.x;
    const int split = blk & (NSPLIT - 1);
    const int bh    = blk / NSPLIT;
    const int b     = bh >> 3;
    const int hd    = bh & 7;
    const int TCH   = DHEAD / NSPLIT;      // 256
    const int t0    = split * TCH;

    __shared__ float qs[8][128];
    __shared__ float ks[8][128];

    const int tid = threadIdx.x;
    const int c0  = (tid & 15) << 3;
    const int e0  = (tid >> 4) << 3;
    const int cc  = tid & 127;
    const int th  = (tid >> 7) << 2;

    float acc[8][8];
    #pragma unroll
    for (int i = 0; i < 8; ++i)
        #pragma unroll
        for (int j = 0; j < 8; ++j) acc[i][j] = 0.f;

    const float* Qb = Q + (size_t)b * CH * HWSZ + hd * DHEAD;
    const float* Kb = K + (size_t)b * CH * HWSZ + hd * DHEAD;

    #pragma unroll 1
    for (int t = t0; t < t0 + TCH; t += 8) {
        const float4 qv = *(const float4*)&Qb[cc * HWSZ + t + th];
        const float4 kv = *(const float4*)&Kb[cc * HWSZ + t + th];
        __syncthreads();
        qs[th + 0][cc] = qv.x; qs[th + 1][cc] = qv.y;
        qs[th + 2][cc] = qv.z; qs[th + 3][cc] = qv.w;
        ks[th + 0][cc] = kv.x; ks[th + 1][cc] = kv.y;
        ks[th + 2][cc] = kv.z; ks[th + 3][cc] = kv.w;
        __syncthreads();
        #pragma unroll
        for (int tt = 0; tt < 8; ++tt) {
            const float4 qa  = *(const float4*)&qs[tt][c0];
            const float4 qb4 = *(const float4*)&qs[tt][c0 + 4];
            const float4 ka  = *(const float4*)&ks[tt][e0];
            const float4 kb4 = *(const float4*)&ks[tt][e0 + 4];
            const float qr[8] = {qa.x, qa.y, qa.z, qa.w, qb4.x, qb4.y, qb4.z, qb4.w};
            const float kr[8] = {ka.x, ka.y, ka.z, ka.w, kb4.x, kb4.y, kb4.z, kb4.w};
            #pragma unroll
            for (int i = 0; i < 8; ++i)
                #pragma unroll
                for (int j = 0; j < 8; ++j)
                    acc[i][j] = fmaf(qr[i], kr[j], acc[i][j]);
        }
    }
    float* Sp = S + (size_t)bh * CH * CH;
    #pragma unroll
    for (int i = 0; i < 8; ++i)
        #pragma unroll
        for (int j = 0; j < 8; ++j)
            atomicAdd(&Sp[(c0 + i) * CH + e0 + j], acc[i][j]);
}

// ---------------- Kernel 3: row softmax of S, in place ------------------------
__global__ __launch_bounds__(256) void softmax_kernel(float* __restrict__ S)
{
    const int row  = blockIdx.x * 4 + (threadIdx.x >> 6);
    const int lane = threadIdx.x & 63;
    float* Sp = S + (size_t)row * CH;
    const float v0 = Sp[lane] * 0.0078125f;
    const float v1 = Sp[lane + 64] * 0.0078125f;
    float m = fmaxf(v0, v1);
    #pragma unroll
    for (int off = 32; off > 0; off >>= 1) m = fmaxf(m, __shfl_down(m, off));
    m = __shfl(m, 0);
    const float e0 = __expf(v0 - m);
    const float e1 = __expf(v1 - m);
    float s = e0 + e1;
    #pragma unroll
    for (int off = 32; off > 0; off >>= 1) s += __shfl_down(s, off);
    s = __shfl(s, 0);
    const float inv = 1.f / s;
    Sp[lane]      = e0 * inv;
    Sp[lane + 64] = e1 * inv;
}

// ---------------- Kernel 4: A = P V, written as At[b][pixel][ci] bf16 ---------
__global__ __launch_bounds__(256) void pv_kernel(
    const float* __restrict__ P, const float* __restrict__ V,
    unsigned short* __restrict__ At)
{
    const int blk = blockIdx.x;
    const int tt0 = (blk & 15) << 7;
    const int bh  = blk >> 4;
    const int b   = bh >> 3;
    const int hd  = bh & 7;

    __shared__ float ps[8][128];
    __shared__ float vs[8][128];

    const int tid = threadIdx.x;
    const int c0  = (tid & 15) << 3;
    const int tl0 = (tid >> 4) << 3;

    const int pcc = tid & 127;
    const int pth = (tid >> 7) << 2;
    const int vr  = tid >> 5;
    const int vc  = (tid & 31) << 2;

    float acc[8][8];
    #pragma unroll
    for (int i = 0; i < 8; ++i)
        #pragma unroll
        for (int j = 0; j < 8; ++j) acc[i][j] = 0.f;

    const float* Pp = P + (size_t)bh * CH * CH;
    const float* Vp = V + (size_t)b * CH * HWSZ + hd * DHEAD + tt0;

    #pragma unroll 1
    for (int e0i = 0; e0i < CH; e0i += 8) {
        const float4 pv4 = *(const float4*)&Pp[pcc * CH + e0i + pth];
        const float4 vv4 = *(const float4*)&Vp[(e0i + vr) * HWSZ + vc];
        __syncthreads();
        ps[pth + 0][pcc] = pv4.x; ps[pth + 1][pcc] = pv4.y;
        ps[pth + 2][pcc] = pv4.z; ps[pth + 3][pcc] = pv4.w;
        *(float4*)&vs[vr][vc] = vv4;
        __syncthreads();
        #pragma unroll
        for (int ee = 0; ee < 8; ++ee) {
            const float4 pa = *(const float4*)&ps[ee][c0];
            const float4 pb = *(const float4*)&ps[ee][c0 + 4];
            const float4 va = *(const float4*)&vs[ee][tl0];
            const float4 vb = *(const float4*)&vs[ee][tl0 + 4];
            const float pr[8] = {pa.x, pa.y, pa.z, pa.w, pb.x, pb.y, pb.z, pb.w};
            const float vr8[8] = {va.x, va.y, va.z, va.w, vb.x, vb.y, vb.z, vb.w};
            #pragma unroll
            for (int i = 0; i < 8; ++i)
                #pragma unroll
                for (int j = 0; j < 8; ++j)
                    acc[i][j] = fmaf(pr[i], vr8[j], acc[i][j]);
        }
    }
    // write transposed bf16: At[((b*HWSZ)+p)*CH + ci]
    const int pbase = hd * DHEAD + tt0 + tl0;
    #pragma unroll
    for (int j = 0; j < 8; ++j) {
        const int p = pbase + j;
        bf16x8 hv;
        #pragma unroll
        for (int i = 0; i < 8; ++i) hv[i] = (short)f2bf(acc[i][j]);
        *(bf16x8*)&At[((size_t)b * HWSZ + p) * CH + c0] = hv;
    }
}

// ---------------- Kernel 5a: weight prep wo fp32 -> Wt[tap][co][ci] bf16 ------
__global__ __launch_bounds__(256) void wprep_kernel(
    const float* __restrict__ wo, unsigned short* __restrict__ Wt)
{
    const int i = blockIdx.x * 256 + threadIdx.x;     // 9*128*128 = 147456
    const int tap = i >> 14;
    const int rem = i & 16383;
    const int co  = rem >> 7;
    const int ci  = rem & 127;
    Wt[i] = f2bf(wo[(size_t)(co * CH + ci) * 9 + tap]);
}

// ---------------- Kernel 5b: 3x3 dense conv via bf16 MFMA implicit GEMM -------
// block = one (b, y) output row: 128 co x 128 px. K = ci*9, looped as
// 9 taps x 2 ci-halves of 64. LDS: act row [x+1][ci] bf16 (pad->136),
// weight chunk [co][ci64] bf16 (pad->72). 4 waves, each 4x4 frags of
// v_mfma_f32_16x16x32_bf16.
__global__ __launch_bounds__(256, 3) void conv3x3_mfma_kernel(
    const unsigned short* __restrict__ At, const unsigned short* __restrict__ Wt,
    const float* __restrict__ bo, float* __restrict__ out)
{
    const int blk = blockIdx.x;
    const int y   = blk & (HH - 1);
    const int b   = blk >> 7;

    __shared__ unsigned short sA[130][136];   // x in -1..128 (+1 offset), ci pad 136
    __shared__ unsigned short sW[128][72];    // co, ci-half pad 72

    const int tid  = threadIdx.x;
    const int wave = tid >> 6;
    const int lane = tid & 63;
    const int lx   = lane & 15;
    const int qd   = lane >> 4;
    const int m0   = (wave & 1) * 64;         // co tile base
    const int n0   = (wave >> 1) * 64;        // x tile base

    // zero halo rows x=-1 and x=128 once (never rewritten).
    // BUGFIX R2->R3: was `sA[r][i & 135]` — 135 is not a pow2-1 mask, so most
    // halo words were never written and held garbage (NaN bf16 patterns).
    for (int i = tid; i < 272; i += 256) {
        const int r   = (i < 136) ? 0 : 129;
        const int col = (i < 136) ? i : (i - 136);
        sA[r][col] = 0;
    }

    // bias preload -> accumulator init
    f32x4 acc[4][4];
    #pragma unroll
    for (int mi = 0; mi < 4; ++mi) {
        f32x4 bv;
        #pragma unroll
        for (int r = 0; r < 4; ++r) bv[r] = bo[m0 + mi * 16 + qd * 4 + r];
        #pragma unroll
        for (int ni = 0; ni < 4; ++ni) acc[mi][ni] = bv;
    }

    const size_t abase = (size_t)b * HWSZ * CH;

    for (int dy = 0; dy < 3; ++dy) {
        const int gy = y + dy - 1;
        __syncthreads();                       // prev compute done
        if ((unsigned)gy < HH) {
            const unsigned short* row = At + abase + (size_t)gy * WW * CH;
            for (int i = tid; i < 2048; i += 256) {
                const int xx  = i >> 4;
                const int cc8 = (i & 15) << 3;
                *(float4*)&sA[xx + 1][cc8] = *(const float4*)&row[xx * CH + cc8];
            }
        } else {
            const float4 z = make_float4(0.f, 0.f, 0.f, 0.f);
            for (int i = tid; i < 2048; i += 256) {
                const int xx  = i >> 4;
                const int cc8 = (i & 15) << 3;
                *(float4*)&sA[xx + 1][cc8] = z;
            }
        }
        for (int dx = 0; dx < 3; ++dx) {
            const int tap = dy * 3 + dx;
            #pragma unroll 1
            for (int kh = 0; kh < 2; ++kh) {
                if (dx | kh) __syncthreads();  // protect sW (and sA reads) reuse
                const unsigned short* wt = Wt + (size_t)tap * CH * CH + kh * 64;
                for (int i = tid; i < 1024; i += 256) {
                    const int co  = i >> 3;
                    const int cc8 = (i & 7) << 3;
                    *(float4*)&sW[co][cc8] = *(const float4*)&wt[co * CH + cc8];
                }
                __syncthreads();
                #pragma unroll
                for (int ks = 0; ks < 2; ++ks) {
                    const int kc  = ks * 32 + qd * 8;          // sW-local ci
                    const int kca = kh * 64 + kc;              // sA ci
                    bf16x8 a[4], bfr[4];
                    #pragma unroll
                    for (int mi = 0; mi < 4; ++mi)
                        a[mi] = *(const bf16x8*)&sW[m0 + mi * 16 + lx][kc];
                    #pragma unroll
                    for (int ni = 0; ni < 4; ++ni)
                        bfr[ni] = *(const bf16x8*)&sA[n0 + ni * 16 + lx + dx][kca];
                    #pragma unroll
                    for (int mi = 0; mi < 4; ++mi)
                        #pragma unroll
                        for (int ni = 0; ni < 4; ++ni)
                            acc[mi][ni] = __builtin_amdgcn_mfma_f32_16x16x32_bf16(
                                a[mi], bfr[ni], acc[mi][ni], 0, 0, 0);
                }
            }
        }
    }

    // epilogue: C/D layout col(n=x)=lane&15, row(m-sub)=qd*4+r
    const size_t obase = (size_t)b * CH * HWSZ + (size_t)y * WW;
    #pragma unroll
    for (int mi = 0; mi < 4; ++mi) {
        #pragma unroll
        for (int r = 0; r < 4; ++r) {
            const int co = m0 + mi * 16 + qd * 4 + r;
            float* orow = out + obase + (size_t)co * HWSZ;
            #pragma unroll
            for (int ni = 0; ni < 4; ++ni)
                orow[n0 + ni * 16 + lx] = acc[mi][ni][r];
        }
    }
}

extern "C" void kernel_launch(void* const* d_in, const int* in_sizes, int n_in,
                              void* d_out, int out_size, void* d_ws, size_t ws_size,
                              hipStream_t stream)
{
    const float* x  = (const float*)d_in[0];
    const float* wq = (const float*)d_in[1];
    const float* bq = (const float*)d_in[2];
    const float* wk = (const float*)d_in[3];
    const float* bk = (const float*)d_in[4];
    const float* wv = (const float*)d_in[5];
    const float* bv = (const float*)d_in[6];
    const float* wo = (const float*)d_in[7];
    const float* bo = (const float*)d_in[8];

    float* Q  = (float*)d_out;                       // consumed before final conv
    char*  ws = (char*)d_ws;
    float* K  = (float*)(ws);                                    // 64 MB
    float* V  = (float*)(ws + (size_t)64 * 1024 * 1024);         // 64 MB
    float* S  = (float*)(ws + (size_t)128 * 1024 * 1024);        // 4 MB
    unsigned short* At = (unsigned short*)(ws + (size_t)132 * 1024 * 1024); // 32 MB
    unsigned short* Wt = (unsigned short*)(ws + (size_t)164 * 1024 * 1024); // 288 KB

    dwconv_qkv_kernel<<<BATCH * CH * 16, 256, 0, stream>>>(x, wq, bq, wk, bk, wv, bv, Q, K, V);
    hipMemsetAsync(S, 0, (size_t)64 * CH * CH * sizeof(float), stream);
    wprep_kernel<<<576, 256, 0, stream>>>(wo, Wt);
    qk_kernel<<<64 * NSPLIT, 256, 0, stream>>>(Q, K, S);
    softmax_kernel<<<2048, 256, 0, stream>>>(S);
    pv_kernel<<<64 * 16, 256, 0, stream>>>(S, V, At);
    conv3x3_mfma_kernel<<<BATCH * HH, 256, 0, stream>>>(At, Wt, bo, (float*)d_out);
}

// Round 5
// 352.115 us; speedup vs baseline: 3.4562x; 1.7862x over previous
//
#include <hip/hip_runtime.h>

#define BATCH 8
#define CH 128
#define HH 128
#define WW 128
#define HWSZ 16384
#define NHEADS 8
#define DHEAD 2048

typedef short bf16x8 __attribute__((ext_vector_type(8)));
typedef short bf16x4v __attribute__((ext_vector_type(4)));
typedef float f32x4 __attribute__((ext_vector_type(4)));

static __device__ inline unsigned short f2bf(float f) {
    unsigned u = __builtin_bit_cast(unsigned, f);
    u += 0x7fff + ((u >> 16) & 1);          // round-to-nearest-even
    return (unsigned short)(u >> 16);
}

// ---------------- Kernel 1: fused depthwise 9x9 conv -> Q,K,V bf16 [bh][c][t] --
__global__ __launch_bounds__(256) void dwconv_qkv_kernel(
    const float* __restrict__ x,
    const float* __restrict__ wq, const float* __restrict__ bq,
    const float* __restrict__ wk, const float* __restrict__ bk,
    const float* __restrict__ wv, const float* __restrict__ bv,
    unsigned short* __restrict__ Qb, unsigned short* __restrict__ Kb,
    unsigned short* __restrict__ Vb)
{
    const int blk  = blockIdx.x;
    const int tile = blk & 15;
    const int bc   = blk >> 4;             // b*128 + c
    const int b    = bc >> 7;
    const int c    = bc & (CH - 1);
    const int ty0  = (tile >> 2) << 5;
    const int tx0  = (tile & 3) << 5;

    __shared__ float sm[40][40];           // 32x32 tile + 4-halo
    const float* xp = x + (size_t)bc * HWSZ;
    const int tid = threadIdx.x;
    for (int i = tid; i < 1600; i += 256) {
        int r = i / 40;
        int col = i - r * 40;
        int gy = ty0 + r - 4;
        int gx = tx0 + col - 4;
        float v = 0.f;
        if ((unsigned)gy < HH && (unsigned)gx < WW) v = xp[gy * WW + gx];
        sm[r][col] = v;
    }
    __syncthreads();

    const float* wqp = wq + c * 81;
    const float* wkp = wk + c * 81;
    const float* wvp = wv + c * 81;

    const int oy = tid >> 3;               // 0..31
    const int ox = (tid & 7) << 2;         // 0,4,...,28

    float accq[4], acck[4], accv[4];
    const float bqv = bq[c], bkv = bk[c], bvv = bv[c];
    #pragma unroll
    for (int j = 0; j < 4; ++j) { accq[j] = bqv; acck[j] = bkv; accv[j] = bvv; }

    for (int dy = 0; dy < 9; ++dy) {
        const float4* rp = (const float4*)&sm[oy + dy][ox];
        const float4 v0 = rp[0], v1 = rp[1], v2 = rp[2];
        const float vals[12] = {v0.x, v0.y, v0.z, v0.w, v1.x, v1.y, v1.z, v1.w,
                                v2.x, v2.y, v2.z, v2.w};
        #pragma unroll
        for (int dx = 0; dx < 9; ++dx) {
            const float wqv = wqp[dy * 9 + dx];
            const float wkv = wkp[dy * 9 + dx];
            const float wvv = wvp[dy * 9 + dx];
            #pragma unroll
            for (int j = 0; j < 4; ++j) {
                const float xv = vals[dx + j];
                accq[j] = fmaf(wqv, xv, accq[j]);
                acck[j] = fmaf(wkv, xv, acck[j]);
                accv[j] = fmaf(wvv, xv, accv[j]);
            }
        }
    }
    // bf16 [bh][c][t]: hd = y>>4, t = (y&15)*128 + x
    const int y = ty0 + oy;
    const size_t off = ((size_t)(b * 8 + (y >> 4)) * CH + c) * DHEAD
                     + (size_t)(y & 15) * WW + tx0 + ox;
    bf16x4v hq, hk, hv;
    #pragma unroll
    for (int j = 0; j < 4; ++j) {
        hq[j] = (short)f2bf(accq[j]);
        hk[j] = (short)f2bf(acck[j]);
        hv[j] = (short)f2bf(accv[j]);
    }
    *(bf16x4v*)&Qb[off] = hq;
    *(bf16x4v*)&Kb[off] = hk;
    *(bf16x4v*)&Vb[off] = hv;
}

// ---------------- Kernel 2: Spart[split][bh] = Q_chunk K_chunk^T via MFMA ------
// NT GEMM: A = Q[c][t], B = K[e][t] — both K(t)-contiguous. 512 blocks.
__global__ __launch_bounds__(256) void qk_mfma_kernel(
    const unsigned short* __restrict__ Qb, const unsigned short* __restrict__ Kb,
    float* __restrict__ Spart)
{
    const int blk   = blockIdx.x;
    const int split = blk & 7;
    const int bh    = blk >> 3;
    const int t0    = split * 256;

    __shared__ unsigned short Qs[128][72];
    __shared__ unsigned short Ks[128][72];

    const int tid  = threadIdx.x;
    const int wave = tid >> 6;
    const int lane = tid & 63;
    const int lx   = lane & 15;
    const int qd   = lane >> 4;
    const int m0   = (wave & 1) * 64;
    const int n0   = (wave >> 1) * 64;

    f32x4 acc[4][4];
    #pragma unroll
    for (int mi = 0; mi < 4; ++mi)
        #pragma unroll
        for (int ni = 0; ni < 4; ++ni) acc[mi][ni] = (f32x4){0.f, 0.f, 0.f, 0.f};

    const unsigned short* Qp = Qb + (size_t)bh * CH * DHEAD;
    const unsigned short* Kp = Kb + (size_t)bh * CH * DHEAD;

    #pragma unroll 1
    for (int tc = 0; tc < 256; tc += 64) {
        __syncthreads();
        for (int i = tid; i < 1024; i += 256) {
            const int r  = i >> 3;
            const int cl = (i & 7) << 3;
            *(bf16x8*)&Qs[r][cl] = *(const bf16x8*)&Qp[(size_t)r * DHEAD + t0 + tc + cl];
            *(bf16x8*)&Ks[r][cl] = *(const bf16x8*)&Kp[(size_t)r * DHEAD + t0 + tc + cl];
        }
        __syncthreads();
        #pragma unroll
        for (int ki = 0; ki < 2; ++ki) {
            const int kc = ki * 32 + qd * 8;
            bf16x8 a[4], bv[4];
            #pragma unroll
            for (int mi = 0; mi < 4; ++mi)
                a[mi] = *(const bf16x8*)&Qs[m0 + mi * 16 + lx][kc];
            #pragma unroll
            for (int ni = 0; ni < 4; ++ni)
                bv[ni] = *(const bf16x8*)&Ks[n0 + ni * 16 + lx][kc];
            #pragma unroll
            for (int mi = 0; mi < 4; ++mi)
                #pragma unroll
                for (int ni = 0; ni < 4; ++ni)
                    acc[mi][ni] = __builtin_amdgcn_mfma_f32_16x16x32_bf16(
                        a[mi], bv[ni], acc[mi][ni], 0, 0, 0);
        }
    }
    // Spart[split][bh][c][e], C/D: col=e=lane&15, row=c=qd*4+r
    float* Sp = Spart + ((size_t)split * 64 + bh) * (CH * CH);
    #pragma unroll
    for (int mi = 0; mi < 4; ++mi)
        #pragma unroll
        for (int r = 0; r < 4; ++r) {
            const int c = m0 + mi * 16 + qd * 4 + r;
            #pragma unroll
            for (int ni = 0; ni < 4; ++ni)
                Sp[c * CH + n0 + ni * 16 + lx] = acc[mi][ni][r];
        }
}

// ---------------- Kernel 3: reduce 8 partials + row softmax -> P bf16 [c][e] ---
__global__ __launch_bounds__(256) void softmax_kernel(
    const float* __restrict__ Spart, unsigned short* __restrict__ Pb)
{
    const int row  = blockIdx.x * 4 + (threadIdx.x >> 6);   // bh*128 + c
    const int lane = threadIdx.x & 63;
    float v0 = 0.f, v1 = 0.f;
    #pragma unroll
    for (int s = 0; s < 8; ++s) {
        const float* Sp = Spart + (size_t)s * 64 * CH * CH + (size_t)row * CH;
        v0 += Sp[lane];
        v1 += Sp[lane + 64];
    }
    v0 *= 0.0078125f; v1 *= 0.0078125f;
    float m = fmaxf(v0, v1);
    #pragma unroll
    for (int off = 32; off > 0; off >>= 1) m = fmaxf(m, __shfl_down(m, off));
    m = __shfl(m, 0);
    const float e0 = __expf(v0 - m);
    const float e1 = __expf(v1 - m);
    float s = e0 + e1;
    #pragma unroll
    for (int off = 32; off > 0; off >>= 1) s += __shfl_down(s, off);
    s = __shfl(s, 0);
    const float inv = 1.f / s;
    Pb[(size_t)row * CH + lane]      = f2bf(e0 * inv);
    Pb[(size_t)row * CH + lane + 64] = f2bf(e1 * inv);
}

// ---------------- Kernel 4: A = P V via MFMA, out At[b][p][ci] bf16 ------------
__global__ __launch_bounds__(256) void pv_mfma_kernel(
    const unsigned short* __restrict__ Pb, const unsigned short* __restrict__ Vb,
    unsigned short* __restrict__ At)
{
    const int blk = blockIdx.x;
    const int t0  = (blk & 15) << 7;
    const int bh  = blk >> 4;

    __shared__ __align__(16) char smem[69632];
    unsigned short (*Ps)[136] = (unsigned short(*)[136])smem;            // 34816 B
    unsigned short (*Vs)[136] = (unsigned short(*)[136])(smem + 34816);  // 34816 B
    float (*So)[132] = (float(*)[132])smem;                              // 67584 B (reused)

    const int tid  = threadIdx.x;
    const int wave = tid >> 6;
    const int lane = tid & 63;
    const int lx   = lane & 15;
    const int qd   = lane >> 4;
    const int m0   = (wave & 1) * 64;      // c tile
    const int n0   = (wave >> 1) * 64;     // t tile

    const unsigned short* Pp = Pb + (size_t)bh * CH * CH;
    const unsigned short* Vp = Vb + (size_t)bh * CH * DHEAD;

    // stage P [c][e]
    for (int i = tid; i < 2048; i += 256) {
        const int r  = i >> 4;
        const int cl = (i & 15) << 3;
        *(bf16x8*)&Ps[r][cl] = *(const bf16x8*)&Pp[(size_t)r * CH + cl];
    }
    // stage V^T: lanes along e (conflict-free 2-way LDS writes)
    for (int i = tid; i < 2048; i += 256) {
        const int e   = i & 127;
        const int tc8 = (i >> 7) << 3;
        const bf16x8 vv = *(const bf16x8*)&Vp[(size_t)e * DHEAD + t0 + tc8];
        #pragma unroll
        for (int j = 0; j < 8; ++j) Vs[tc8 + j][e] = (unsigned short)vv[j];
    }
    __syncthreads();

    f32x4 acc[4][4];
    #pragma unroll
    for (int mi = 0; mi < 4; ++mi)
        #pragma unroll
        for (int ni = 0; ni < 4; ++ni) acc[mi][ni] = (f32x4){0.f, 0.f, 0.f, 0.f};

    #pragma unroll
    for (int ki = 0; ki < 4; ++ki) {
        const int kc = ki * 32 + qd * 8;
        bf16x8 a[4], bv[4];
        #pragma unroll
        for (int mi = 0; mi < 4; ++mi)
            a[mi] = *(const bf16x8*)&Ps[m0 + mi * 16 + lx][kc];
        #pragma unroll
        for (int ni = 0; ni < 4; ++ni)
            bv[ni] = *(const bf16x8*)&Vs[n0 + ni * 16 + lx][kc];
        #pragma unroll
        for (int mi = 0; mi < 4; ++mi)
            #pragma unroll
            for (int ni = 0; ni < 4; ++ni)
                acc[mi][ni] = __builtin_amdgcn_mfma_f32_16x16x32_bf16(
                    a[mi], bv[ni], acc[mi][ni], 0, 0, 0);
    }

    // transpose through LDS: So[t][c]
    __syncthreads();
    #pragma unroll
    for (int mi = 0; mi < 4; ++mi)
        #pragma unroll
        for (int ni = 0; ni < 4; ++ni)
            #pragma unroll
            for (int r = 0; r < 4; ++r)
                So[n0 + ni * 16 + lx][m0 + mi * 16 + qd * 4 + r] = acc[mi][ni][r];
    __syncthreads();

    // coalesced bf16 store: At[((b*HWSZ) + hd*2048 + t0 + t)*128 + c]
    const int t  = tid >> 1;
    const int ch = (tid & 1) * 64;
    const size_t orow = (((size_t)(bh >> 3) * HWSZ) + (size_t)(bh & 7) * DHEAD + t0 + t) * CH + ch;
    #pragma unroll
    for (int j = 0; j < 8; ++j) {
        const float4 f0 = *(const float4*)&So[t][ch + j * 8];
        const float4 f1 = *(const float4*)&So[t][ch + j * 8 + 4];
        bf16x8 h;
        h[0] = (short)f2bf(f0.x); h[1] = (short)f2bf(f0.y);
        h[2] = (short)f2bf(f0.z); h[3] = (short)f2bf(f0.w);
        h[4] = (short)f2bf(f1.x); h[5] = (short)f2bf(f1.y);
        h[6] = (short)f2bf(f1.z); h[7] = (short)f2bf(f1.w);
        *(bf16x8*)&At[orow + j * 8] = h;
    }
}

// ---------------- Kernel 5a: weight prep wo fp32 -> Wt[tap][co][ci] bf16 ------
__global__ __launch_bounds__(256) void wprep_kernel(
    const float* __restrict__ wo, unsigned short* __restrict__ Wt)
{
    const int i = blockIdx.x * 256 + threadIdx.x;     // 9*128*128 = 147456
    const int tap = i >> 14;
    const int rem = i & 16383;
    const int co  = rem >> 7;
    const int ci  = rem & 127;
    Wt[i] = f2bf(wo[(size_t)(co * CH + ci) * 9 + tap]);
}

// ---------------- Kernel 5b: 3x3 dense conv via bf16 MFMA implicit GEMM -------
__global__ __launch_bounds__(256, 3) void conv3x3_mfma_kernel(
    const unsigned short* __restrict__ At, const unsigned short* __restrict__ Wt,
    const float* __restrict__ bo, float* __restrict__ out)
{
    const int blk = blockIdx.x;
    const int y   = blk & (HH - 1);
    const int b   = blk >> 7;

    __shared__ unsigned short sA[130][136];   // x in -1..128 (+1 offset)
    __shared__ unsigned short sW[128][72];

    const int tid  = threadIdx.x;
    const int wave = tid >> 6;
    const int lane = tid & 63;
    const int lx   = lane & 15;
    const int qd   = lane >> 4;
    const int m0   = (wave & 1) * 64;
    const int n0   = (wave >> 1) * 64;

    for (int i = tid; i < 272; i += 256) {
        const int r   = (i < 136) ? 0 : 129;
        const int col = (i < 136) ? i : (i - 136);
        sA[r][col] = 0;
    }

    f32x4 acc[4][4];
    #pragma unroll
    for (int mi = 0; mi < 4; ++mi) {
        f32x4 bv;
        #pragma unroll
        for (int r = 0; r < 4; ++r) bv[r] = bo[m0 + mi * 16 + qd * 4 + r];
        #pragma unroll
        for (int ni = 0; ni < 4; ++ni) acc[mi][ni] = bv;
    }

    const size_t abase = (size_t)b * HWSZ * CH;

    for (int dy = 0; dy < 3; ++dy) {
        const int gy = y + dy - 1;
        __syncthreads();
        if ((unsigned)gy < HH) {
            const unsigned short* row = At + abase + (size_t)gy * WW * CH;
            for (int i = tid; i < 2048; i += 256) {
                const int xx  = i >> 4;
                const int cc8 = (i & 15) << 3;
                *(float4*)&sA[xx + 1][cc8] = *(const float4*)&row[xx * CH + cc8];
            }
        } else {
            const float4 z = make_float4(0.f, 0.f, 0.f, 0.f);
            for (int i = tid; i < 2048; i += 256) {
                const int xx  = i >> 4;
                const int cc8 = (i & 15) << 3;
                *(float4*)&sA[xx + 1][cc8] = z;
            }
        }
        for (int dx = 0; dx < 3; ++dx) {
            const int tap = dy * 3 + dx;
            #pragma unroll 1
            for (int kh = 0; kh < 2; ++kh) {
                if (dx | kh) __syncthreads();
                const unsigned short* wt = Wt + (size_t)tap * CH * CH + kh * 64;
                for (int i = tid; i < 1024; i += 256) {
                    const int co  = i >> 3;
                    const int cc8 = (i & 7) << 3;
                    *(float4*)&sW[co][cc8] = *(const float4*)&wt[co * CH + cc8];
                }
                __syncthreads();
                #pragma unroll
                for (int ks = 0; ks < 2; ++ks) {
                    const int kc  = ks * 32 + qd * 8;
                    const int kca = kh * 64 + kc;
                    bf16x8 a[4], bfr[4];
                    #pragma unroll
                    for (int mi = 0; mi < 4; ++mi)
                        a[mi] = *(const bf16x8*)&sW[m0 + mi * 16 + lx][kc];
                    #pragma unroll
                    for (int ni = 0; ni < 4; ++ni)
                        bfr[ni] = *(const bf16x8*)&sA[n0 + ni * 16 + lx + dx][kca];
                    #pragma unroll
                    for (int mi = 0; mi < 4; ++mi)
                        #pragma unroll
                        for (int ni = 0; ni < 4; ++ni)
                            acc[mi][ni] = __builtin_amdgcn_mfma_f32_16x16x32_bf16(
                                a[mi], bfr[ni], acc[mi][ni], 0, 0, 0);
                }
            }
        }
    }

    const size_t obase = (size_t)b * CH * HWSZ + (size_t)y * WW;
    #pragma unroll
    for (int mi = 0; mi < 4; ++mi) {
        #pragma unroll
        for (int r = 0; r < 4; ++r) {
            const int co = m0 + mi * 16 + qd * 4 + r;
            float* orow = out + obase + (size_t)co * HWSZ;
            #pragma unroll
            for (int ni = 0; ni < 4; ++ni)
                orow[n0 + ni * 16 + lx] = acc[mi][ni][r];
        }
    }
}

extern "C" void kernel_launch(void* const* d_in, const int* in_sizes, int n_in,
                              void* d_out, int out_size, void* d_ws, size_t ws_size,
                              hipStream_t stream)
{
    const float* x  = (const float*)d_in[0];
    const float* wq = (const float*)d_in[1];
    const float* bq = (const float*)d_in[2];
    const float* wk = (const float*)d_in[3];
    const float* bk = (const float*)d_in[4];
    const float* wv = (const float*)d_in[5];
    const float* bv = (const float*)d_in[6];
    const float* wo = (const float*)d_in[7];
    const float* bo = (const float*)d_in[8];

    // Workspace layout (BUGFIX R4->R5: Wt previously at 168869888, inside
    // At's [136314880, 169869312) range — pv_mfma clobbered all weights).
    char* ws = (char*)d_ws;
    unsigned short* Qb    = (unsigned short*)(ws);                        // 32 MiB
    unsigned short* Kb    = (unsigned short*)(ws + (size_t)33554432);     // 32 MiB
    unsigned short* Vb    = (unsigned short*)(ws + (size_t)67108864);     // 32 MiB
    float*          Spart = (float*)        (ws + (size_t)100663296);     // 32 MiB
    unsigned short* Pb    = (unsigned short*)(ws + (size_t)134217728);    // 2 MiB
    unsigned short* At    = (unsigned short*)(ws + (size_t)136314880);    // 32 MiB -> ends 169869312
    unsigned short* Wt    = (unsigned short*)(ws + (size_t)169869312);    // 288 KiB

    dwconv_qkv_kernel<<<BATCH * CH * 16, 256, 0, stream>>>(x, wq, bq, wk, bk, wv, bv, Qb, Kb, Vb);
    wprep_kernel<<<576, 256, 0, stream>>>(wo, Wt);
    qk_mfma_kernel<<<64 * 8, 256, 0, stream>>>(Qb, Kb, Spart);
    softmax_kernel<<<2048, 256, 0, stream>>>(Spart, Pb);
    pv_mfma_kernel<<<64 * 16, 256, 0, stream>>>(Pb, Vb, At);
    conv3x3_mfma_kernel<<<BATCH * HH, 256, 0, stream>>>(At, Wt, bo, (float*)d_out);
}

// Round 6
// 339.266 us; speedup vs baseline: 3.5871x; 1.0379x over previous
//
#include <hip/hip_runtime.h>

#define BATCH 8
#define CH 128
#define HH 128
#define WW 128
#define HWSZ 16384
#define NHEADS 8
#define DHEAD 2048

typedef short bf16x8 __attribute__((ext_vector_type(8)));
typedef short bf16x4v __attribute__((ext_vector_type(4)));
typedef float f32x4 __attribute__((ext_vector_type(4)));

static __device__ inline unsigned short f2bf(float f) {
    unsigned u = __builtin_bit_cast(unsigned, f);
    u += 0x7fff + ((u >> 16) & 1);          // round-to-nearest-even
    return (unsigned short)(u >> 16);
}

// ---------------- Kernel 1: fused depthwise 9x9 conv -> Q,K,V bf16 [bh][c][t] --
// R6: 2y x 4x register tile per thread; each input row read once (30 b128 for
// 1944 FMA vs 27 for 972 before). Block = 64x32 tile; grid B*C*8.
__global__ __launch_bounds__(256) void dwconv_qkv_kernel(
    const float* __restrict__ x,
    const float* __restrict__ wq, const float* __restrict__ bq,
    const float* __restrict__ wk, const float* __restrict__ bk,
    const float* __restrict__ wv, const float* __restrict__ bv,
    unsigned short* __restrict__ Qb, unsigned short* __restrict__ Kb,
    unsigned short* __restrict__ Vb)
{
    const int blk  = blockIdx.x;
    const int tile = blk & 7;              // 2 x-tiles * 4 y-tiles
    const int bc   = blk >> 3;             // b*128 + c
    const int b    = bc >> 7;
    const int c    = bc & (CH - 1);
    const int ty0  = (tile >> 1) << 5;     // 0,32,64,96
    const int tx0  = (tile & 1) << 6;      // 0,64

    __shared__ float sm[40][76];           // 32x64 tile + 4-halo, stride 76
    const float* xp = x + (size_t)bc * HWSZ;
    const int tid = threadIdx.x;
    for (int i = tid; i < 2880; i += 256) {
        const int r   = i / 72;
        const int col = i - r * 72;
        const int gy  = ty0 + r - 4;
        const int gx  = tx0 + col - 4;
        float v = 0.f;
        if ((unsigned)gy < HH && (unsigned)gx < WW) v = xp[gy * WW + gx];
        sm[r][col] = v;
    }
    __syncthreads();

    const float* wqp = wq + c * 81;        // uniform -> s_load
    const float* wkp = wk + c * 81;
    const float* wvp = wv + c * 81;

    const int tx  = tid & 15;
    const int ty  = tid >> 4;              // 0..15
    const int x0  = tx << 2;               // 0..60 (local)
    const int oy0 = ty << 1;               // 0..30 (local)

    float accq[2][4], acck[2][4], accv[2][4];
    const float bqv = bq[c], bkv = bk[c], bvv = bv[c];
    #pragma unroll
    for (int yy = 0; yy < 2; ++yy)
        #pragma unroll
        for (int j = 0; j < 4; ++j) { accq[yy][j] = bqv; acck[yy][j] = bkv; accv[yy][j] = bvv; }

    #pragma unroll
    for (int r = 0; r < 10; ++r) {
        const float4* rp = (const float4*)&sm[oy0 + r][x0];
        const float4 v0 = rp[0], v1 = rp[1], v2 = rp[2];
        const float vals[12] = {v0.x, v0.y, v0.z, v0.w, v1.x, v1.y, v1.z, v1.w,
                                v2.x, v2.y, v2.z, v2.w};
        #pragma unroll
        for (int yy = 0; yy < 2; ++yy) {
            const int dy = r - yy;
            if (dy < 0 || dy > 8) continue;   // compile-time after unroll
            #pragma unroll
            for (int dx = 0; dx < 9; ++dx) {
                const float wqv = wqp[dy * 9 + dx];
                const float wkv = wkp[dy * 9 + dx];
                const float wvv = wvp[dy * 9 + dx];
                #pragma unroll
                for (int j = 0; j < 4; ++j) {
                    const float xv = vals[dx + j];
                    accq[yy][j] = fmaf(wqv, xv, accq[yy][j]);
                    acck[yy][j] = fmaf(wkv, xv, acck[yy][j]);
                    accv[yy][j] = fmaf(wvv, xv, accv[yy][j]);
                }
            }
        }
    }

    // bf16 [bh][c][t]: hd = y>>4, t = (y&15)*128 + x
    #pragma unroll
    for (int yy = 0; yy < 2; ++yy) {
        const int y = ty0 + oy0 + yy;
        const size_t off = ((size_t)(b * 8 + (y >> 4)) * CH + c) * DHEAD
                         + (size_t)(y & 15) * WW + tx0 + x0;
        bf16x4v hq, hk, hv;
        #pragma unroll
        for (int j = 0; j < 4; ++j) {
            hq[j] = (short)f2bf(accq[yy][j]);
            hk[j] = (short)f2bf(acck[yy][j]);
            hv[j] = (short)f2bf(accv[yy][j]);
        }
        *(bf16x4v*)&Qb[off] = hq;
        *(bf16x4v*)&Kb[off] = hk;
        *(bf16x4v*)&Vb[off] = hv;
    }
}

// ---------------- Kernel 2: Spart[split][bh] = Q_chunk K_chunk^T via MFMA ------
// NT GEMM: A = Q[c][t], B = K[e][t] — both K(t)-contiguous. 512 blocks.
__global__ __launch_bounds__(256) void qk_mfma_kernel(
    const unsigned short* __restrict__ Qb, const unsigned short* __restrict__ Kb,
    float* __restrict__ Spart)
{
    const int blk   = blockIdx.x;
    const int split = blk & 7;
    const int bh    = blk >> 3;
    const int t0    = split * 256;

    __shared__ unsigned short Qs[128][72];
    __shared__ unsigned short Ks[128][72];

    const int tid  = threadIdx.x;
    const int wave = tid >> 6;
    const int lane = tid & 63;
    const int lx   = lane & 15;
    const int qd   = lane >> 4;
    const int m0   = (wave & 1) * 64;
    const int n0   = (wave >> 1) * 64;

    f32x4 acc[4][4];
    #pragma unroll
    for (int mi = 0; mi < 4; ++mi)
        #pragma unroll
        for (int ni = 0; ni < 4; ++ni) acc[mi][ni] = (f32x4){0.f, 0.f, 0.f, 0.f};

    const unsigned short* Qp = Qb + (size_t)bh * CH * DHEAD;
    const unsigned short* Kp = Kb + (size_t)bh * CH * DHEAD;

    #pragma unroll 1
    for (int tc = 0; tc < 256; tc += 64) {
        __syncthreads();
        for (int i = tid; i < 1024; i += 256) {
            const int r  = i >> 3;
            const int cl = (i & 7) << 3;
            *(bf16x8*)&Qs[r][cl] = *(const bf16x8*)&Qp[(size_t)r * DHEAD + t0 + tc + cl];
            *(bf16x8*)&Ks[r][cl] = *(const bf16x8*)&Kp[(size_t)r * DHEAD + t0 + tc + cl];
        }
        __syncthreads();
        #pragma unroll
        for (int ki = 0; ki < 2; ++ki) {
            const int kc = ki * 32 + qd * 8;
            bf16x8 a[4], bv[4];
            #pragma unroll
            for (int mi = 0; mi < 4; ++mi)
                a[mi] = *(const bf16x8*)&Qs[m0 + mi * 16 + lx][kc];
            #pragma unroll
            for (int ni = 0; ni < 4; ++ni)
                bv[ni] = *(const bf16x8*)&Ks[n0 + ni * 16 + lx][kc];
            #pragma unroll
            for (int mi = 0; mi < 4; ++mi)
                #pragma unroll
                for (int ni = 0; ni < 4; ++ni)
                    acc[mi][ni] = __builtin_amdgcn_mfma_f32_16x16x32_bf16(
                        a[mi], bv[ni], acc[mi][ni], 0, 0, 0);
        }
    }
    // Spart[split][bh][c][e], C/D: col=e=lane&15, row=c=qd*4+r
    float* Sp = Spart + ((size_t)split * 64 + bh) * (CH * CH);
    #pragma unroll
    for (int mi = 0; mi < 4; ++mi)
        #pragma unroll
        for (int r = 0; r < 4; ++r) {
            const int c = m0 + mi * 16 + qd * 4 + r;
            #pragma unroll
            for (int ni = 0; ni < 4; ++ni)
                Sp[c * CH + n0 + ni * 16 + lx] = acc[mi][ni][r];
        }
}

// ---------------- Kernel 3: reduce 8 partials + row softmax -> P bf16 [c][e] ---
__global__ __launch_bounds__(256) void softmax_kernel(
    const float* __restrict__ Spart, unsigned short* __restrict__ Pb)
{
    const int row  = blockIdx.x * 4 + (threadIdx.x >> 6);   // bh*128 + c
    const int lane = threadIdx.x & 63;
    float v0 = 0.f, v1 = 0.f;
    #pragma unroll
    for (int s = 0; s < 8; ++s) {
        const float* Sp = Spart + (size_t)s * 64 * CH * CH + (size_t)row * CH;
        v0 += Sp[lane];
        v1 += Sp[lane + 64];
    }
    v0 *= 0.0078125f; v1 *= 0.0078125f;
    float m = fmaxf(v0, v1);
    #pragma unroll
    for (int off = 32; off > 0; off >>= 1) m = fmaxf(m, __shfl_down(m, off));
    m = __shfl(m, 0);
    const float e0 = __expf(v0 - m);
    const float e1 = __expf(v1 - m);
    float s = e0 + e1;
    #pragma unroll
    for (int off = 32; off > 0; off >>= 1) s += __shfl_down(s, off);
    s = __shfl(s, 0);
    const float inv = 1.f / s;
    Pb[(size_t)row * CH + lane]      = f2bf(e0 * inv);
    Pb[(size_t)row * CH + lane + 64] = f2bf(e1 * inv);
}

// ---------------- Kernel 4: A = P V via MFMA, out At[b][p][ci] bf16 ------------
__global__ __launch_bounds__(256) void pv_mfma_kernel(
    const unsigned short* __restrict__ Pb, const unsigned short* __restrict__ Vb,
    unsigned short* __restrict__ At)
{
    const int blk = blockIdx.x;
    const int t0  = (blk & 15) << 7;
    const int bh  = blk >> 4;

    __shared__ __align__(16) char smem[69632];
    unsigned short (*Ps)[136] = (unsigned short(*)[136])smem;            // 34816 B
    unsigned short (*Vs)[136] = (unsigned short(*)[136])(smem + 34816);  // 34816 B
    float (*So)[132] = (float(*)[132])smem;                              // 67584 B (reused)

    const int tid  = threadIdx.x;
    const int wave = tid >> 6;
    const int lane = tid & 63;
    const int lx   = lane & 15;
    const int qd   = lane >> 4;
    const int m0   = (wave & 1) * 64;      // c tile
    const int n0   = (wave >> 1) * 64;     // t tile

    const unsigned short* Pp = Pb + (size_t)bh * CH * CH;
    const unsigned short* Vp = Vb + (size_t)bh * CH * DHEAD;

    // stage P [c][e]
    for (int i = tid; i < 2048; i += 256) {
        const int r  = i >> 4;
        const int cl = (i & 15) << 3;
        *(bf16x8*)&Ps[r][cl] = *(const bf16x8*)&Pp[(size_t)r * CH + cl];
    }
    // stage V^T: lanes along e (conflict-free 2-way LDS writes)
    for (int i = tid; i < 2048; i += 256) {
        const int e   = i & 127;
        const int tc8 = (i >> 7) << 3;
        const bf16x8 vv = *(const bf16x8*)&Vp[(size_t)e * DHEAD + t0 + tc8];
        #pragma unroll
        for (int j = 0; j < 8; ++j) Vs[tc8 + j][e] = (unsigned short)vv[j];
    }
    __syncthreads();

    f32x4 acc[4][4];
    #pragma unroll
    for (int mi = 0; mi < 4; ++mi)
        #pragma unroll
        for (int ni = 0; ni < 4; ++ni) acc[mi][ni] = (f32x4){0.f, 0.f, 0.f, 0.f};

    #pragma unroll
    for (int ki = 0; ki < 4; ++ki) {
        const int kc = ki * 32 + qd * 8;
        bf16x8 a[4], bv[4];
        #pragma unroll
        for (int mi = 0; mi < 4; ++mi)
            a[mi] = *(const bf16x8*)&Ps[m0 + mi * 16 + lx][kc];
        #pragma unroll
        for (int ni = 0; ni < 4; ++ni)
            bv[ni] = *(const bf16x8*)&Vs[n0 + ni * 16 + lx][kc];
        #pragma unroll
        for (int mi = 0; mi < 4; ++mi)
            #pragma unroll
            for (int ni = 0; ni < 4; ++ni)
                acc[mi][ni] = __builtin_amdgcn_mfma_f32_16x16x32_bf16(
                    a[mi], bv[ni], acc[mi][ni], 0, 0, 0);
    }

    // transpose through LDS: So[t][c]
    __syncthreads();
    #pragma unroll
    for (int mi = 0; mi < 4; ++mi)
        #pragma unroll
        for (int ni = 0; ni < 4; ++ni)
            #pragma unroll
            for (int r = 0; r < 4; ++r)
                So[n0 + ni * 16 + lx][m0 + mi * 16 + qd * 4 + r] = acc[mi][ni][r];
    __syncthreads();

    // coalesced bf16 store: At[((b*HWSZ) + hd*2048 + t0 + t)*128 + c]
    const int t  = tid >> 1;
    const int ch = (tid & 1) * 64;
    const size_t orow = (((size_t)(bh >> 3) * HWSZ) + (size_t)(bh & 7) * DHEAD + t0 + t) * CH + ch;
    #pragma unroll
    for (int j = 0; j < 8; ++j) {
        const float4 f0 = *(const float4*)&So[t][ch + j * 8];
        const float4 f1 = *(const float4*)&So[t][ch + j * 8 + 4];
        bf16x8 h;
        h[0] = (short)f2bf(f0.x); h[1] = (short)f2bf(f0.y);
        h[2] = (short)f2bf(f0.z); h[3] = (short)f2bf(f0.w);
        h[4] = (short)f2bf(f1.x); h[5] = (short)f2bf(f1.y);
        h[6] = (short)f2bf(f1.z); h[7] = (short)f2bf(f1.w);
        *(bf16x8*)&At[orow + j * 8] = h;
    }
}

// ---------------- Kernel 5a: weight prep wo fp32 -> Wt[tap][co][ci] bf16 ------
__global__ __launch_bounds__(256) void wprep_kernel(
    const float* __restrict__ wo, unsigned short* __restrict__ Wt)
{
    const int i = blockIdx.x * 256 + threadIdx.x;     // 9*128*128 = 147456
    const int tap = i >> 14;
    const int rem = i & 16383;
    const int co  = rem >> 7;
    const int ci  = rem & 127;
    Wt[i] = f2bf(wo[(size_t)(co * CH + ci) * 9 + tap]);
}

// ---------------- Kernel 5b: 3x3 dense conv via bf16 MFMA implicit GEMM -------
__global__ __launch_bounds__(256, 3) void conv3x3_mfma_kernel(
    const unsigned short* __restrict__ At, const unsigned short* __restrict__ Wt,
    const float* __restrict__ bo, float* __restrict__ out)
{
    const int blk = blockIdx.x;
    const int y   = blk & (HH - 1);
    const int b   = blk >> 7;

    __shared__ unsigned short sA[130][136];   // x in -1..128 (+1 offset)
    __shared__ unsigned short sW[128][72];

    const int tid  = threadIdx.x;
    const int wave = tid >> 6;
    const int lane = tid & 63;
    const int lx   = lane & 15;
    const int qd   = lane >> 4;
    const int m0   = (wave & 1) * 64;
    const int n0   = (wave >> 1) * 64;

    for (int i = tid; i < 272; i += 256) {
        const int r   = (i < 136) ? 0 : 129;
        const int col = (i < 136) ? i : (i - 136);
        sA[r][col] = 0;
    }

    f32x4 acc[4][4];
    #pragma unroll
    for (int mi = 0; mi < 4; ++mi) {
        f32x4 bv;
        #pragma unroll
        for (int r = 0; r < 4; ++r) bv[r] = bo[m0 + mi * 16 + qd * 4 + r];
        #pragma unroll
        for (int ni = 0; ni < 4; ++ni) acc[mi][ni] = bv;
    }

    const size_t abase = (size_t)b * HWSZ * CH;

    for (int dy = 0; dy < 3; ++dy) {
        const int gy = y + dy - 1;
        __syncthreads();
        if ((unsigned)gy < HH) {
            const unsigned short* row = At + abase + (size_t)gy * WW * CH;
            for (int i = tid; i < 2048; i += 256) {
                const int xx  = i >> 4;
                const int cc8 = (i & 15) << 3;
                *(float4*)&sA[xx + 1][cc8] = *(const float4*)&row[xx * CH + cc8];
            }
        } else {
            const float4 z = make_float4(0.f, 0.f, 0.f, 0.f);
            for (int i = tid; i < 2048; i += 256) {
                const int xx  = i >> 4;
                const int cc8 = (i & 15) << 3;
                *(float4*)&sA[xx + 1][cc8] = z;
            }
        }
        for (int dx = 0; dx < 3; ++dx) {
            const int tap = dy * 3 + dx;
            #pragma unroll 1
            for (int kh = 0; kh < 2; ++kh) {
                if (dx | kh) __syncthreads();
                const unsigned short* wt = Wt + (size_t)tap * CH * CH + kh * 64;
                for (int i = tid; i < 1024; i += 256) {
                    const int co  = i >> 3;
                    const int cc8 = (i & 7) << 3;
                    *(float4*)&sW[co][cc8] = *(const float4*)&wt[co * CH + cc8];
                }
                __syncthreads();
                #pragma unroll
                for (int ks = 0; ks < 2; ++ks) {
                    const int kc  = ks * 32 + qd * 8;
                    const int kca = kh * 64 + kc;
                    bf16x8 a[4], bfr[4];
                    #pragma unroll
                    for (int mi = 0; mi < 4; ++mi)
                        a[mi] = *(const bf16x8*)&sW[m0 + mi * 16 + lx][kc];
                    #pragma unroll
                    for (int ni = 0; ni < 4; ++ni)
                        bfr[ni] = *(const bf16x8*)&sA[n0 + ni * 16 + lx + dx][kca];
                    #pragma unroll
                    for (int mi = 0; mi < 4; ++mi)
                        #pragma unroll
                        for (int ni = 0; ni < 4; ++ni)
                            acc[mi][ni] = __builtin_amdgcn_mfma_f32_16x16x32_bf16(
                                a[mi], bfr[ni], acc[mi][ni], 0, 0, 0);
                }
            }
        }
    }

    const size_t obase = (size_t)b * CH * HWSZ + (size_t)y * WW;
    #pragma unroll
    for (int mi = 0; mi < 4; ++mi) {
        #pragma unroll
        for (int r = 0; r < 4; ++r) {
            const int co = m0 + mi * 16 + qd * 4 + r;
            float* orow = out + obase + (size_t)co * HWSZ;
            #pragma unroll
            for (int ni = 0; ni < 4; ++ni)
                orow[n0 + ni * 16 + lx] = acc[mi][ni][r];
        }
    }
}

extern "C" void kernel_launch(void* const* d_in, const int* in_sizes, int n_in,
                              void* d_out, int out_size, void* d_ws, size_t ws_size,
                              hipStream_t stream)
{
    const float* x  = (const float*)d_in[0];
    const float* wq = (const float*)d_in[1];
    const float* bq = (const float*)d_in[2];
    const float* wk = (const float*)d_in[3];
    const float* bk = (const float*)d_in[4];
    const float* wv = (const float*)d_in[5];
    const float* bv = (const float*)d_in[6];
    const float* wo = (const float*)d_in[7];
    const float* bo = (const float*)d_in[8];

    char* ws = (char*)d_ws;
    unsigned short* Qb    = (unsigned short*)(ws);                        // 32 MiB
    unsigned short* Kb    = (unsigned short*)(ws + (size_t)33554432);     // 32 MiB
    unsigned short* Vb    = (unsigned short*)(ws + (size_t)67108864);     // 32 MiB
    float*          Spart = (float*)        (ws + (size_t)100663296);     // 32 MiB
    unsigned short* Pb    = (unsigned short*)(ws + (size_t)134217728);    // 2 MiB
    unsigned short* At    = (unsigned short*)(ws + (size_t)136314880);    // 32 MiB -> ends 169869312
    unsigned short* Wt    = (unsigned short*)(ws + (size_t)169869312);    // 288 KiB

    dwconv_qkv_kernel<<<BATCH * CH * 8, 256, 0, stream>>>(x, wq, bq, wk, bk, wv, bv, Qb, Kb, Vb);
    wprep_kernel<<<576, 256, 0, stream>>>(wo, Wt);
    qk_mfma_kernel<<<64 * 8, 256, 0, stream>>>(Qb, Kb, Spart);
    softmax_kernel<<<2048, 256, 0, stream>>>(Spart, Pb);
    pv_mfma_kernel<<<64 * 16, 256, 0, stream>>>(Pb, Vb, At);
    conv3x3_mfma_kernel<<<BATCH * HH, 256, 0, stream>>>(At, Wt, bo, (float*)d_out);
}

// Round 7
// 323.745 us; speedup vs baseline: 3.7591x; 1.0479x over previous
//
#include <hip/hip_runtime.h>

#define BATCH 8
#define CH 128
#define HH 128
#define WW 128
#define HWSZ 16384
#define NHEADS 8
#define DHEAD 2048

typedef short bf16x8 __attribute__((ext_vector_type(8)));
typedef short bf16x4v __attribute__((ext_vector_type(4)));
typedef float f32x4 __attribute__((ext_vector_type(4)));
typedef float f32x2 __attribute__((ext_vector_type(2)));

static __device__ inline unsigned short f2bf(float f) {
    unsigned u = __builtin_bit_cast(unsigned, f);
    u += 0x7fff + ((u >> 16) & 1);          // round-to-nearest-even
    return (unsigned short)(u >> 16);
}

// ---------------- Kernel 1: fused depthwise 9x9 conv -> Q,K,V bf16 [bh][c][t] --
// R7: 4y x 4x register tile (3888 FMA as 1944 v_pk_fma_f32), float4 staging.
// Block = 64x64 tile; grid B*C*4.
__global__ __launch_bounds__(256) void dwconv_qkv_kernel(
    const float* __restrict__ x,
    const float* __restrict__ wq, const float* __restrict__ bq,
    const float* __restrict__ wk, const float* __restrict__ bk,
    const float* __restrict__ wv, const float* __restrict__ bv,
    unsigned short* __restrict__ Qb, unsigned short* __restrict__ Kb,
    unsigned short* __restrict__ Vb)
{
    const int blk  = blockIdx.x;
    const int tile = blk & 3;              // 2x2 tiles of 64x64
    const int bc   = blk >> 2;             // b*128 + c
    const int b    = bc >> 7;
    const int c    = bc & (CH - 1);
    const int ty0  = (tile >> 1) << 6;     // 0,64
    const int tx0  = (tile & 1) << 6;      // 0,64

    __shared__ float sm[72][76];           // 64x64 tile + 4-halo, stride 76
    const float* xp = x + (size_t)bc * HWSZ;
    const int tid = threadIdx.x;
    // float4 staging: 72 rows x 18 float4; edge float4s are all-in or all-out.
    for (int i = tid; i < 1296; i += 256) {
        const int r  = i / 18;
        const int c4 = (i - r * 18) << 2;  // 0..68
        const int gy = ty0 + r - 4;
        const int gx = tx0 + c4 - 4;
        float4 v = make_float4(0.f, 0.f, 0.f, 0.f);
        if ((unsigned)gy < HH && (unsigned)gx < WW)
            v = *(const float4*)&xp[gy * WW + gx];
        *(float4*)&sm[r][c4] = v;
    }
    __syncthreads();

    const float* wqp = wq + c * 81;        // block-uniform -> s_load
    const float* wkp = wk + c * 81;
    const float* wvp = wv + c * 81;

    const int tx  = tid & 15;
    const int ty  = tid >> 4;              // 0..15
    const int x0  = tx << 2;               // local out x base 0..60
    const int oy0 = ty << 2;               // local out y base 0..60

    f32x2 aq[4][2], ak[4][2], av[4][2];
    const float bqv = bq[c], bkv = bk[c], bvv = bv[c];
    #pragma unroll
    for (int yy = 0; yy < 4; ++yy)
        #pragma unroll
        for (int h = 0; h < 2; ++h) {
            aq[yy][h] = (f32x2){bqv, bqv};
            ak[yy][h] = (f32x2){bkv, bkv};
            av[yy][h] = (f32x2){bvv, bvv};
        }

    #pragma unroll
    for (int r = 0; r < 12; ++r) {
        const float4* rp = (const float4*)&sm[oy0 + r][x0];
        const float4 v0 = rp[0], v1 = rp[1], v2 = rp[2];
        const float vals[12] = {v0.x, v0.y, v0.z, v0.w, v1.x, v1.y, v1.z, v1.w,
                                v2.x, v2.y, v2.z, v2.w};
        #pragma unroll
        for (int dx = 0; dx < 9; ++dx) {
            const f32x2 xa = {vals[dx + 0], vals[dx + 1]};
            const f32x2 xb = {vals[dx + 2], vals[dx + 3]};
            #pragma unroll
            for (int yy = 0; yy < 4; ++yy) {
                const int dy = r - yy;
                if (dy < 0 || dy > 8) continue;   // compile-time after unroll
                const float wqv = wqp[dy * 9 + dx];
                const float wkv = wkp[dy * 9 + dx];
                const float wvv = wvp[dy * 9 + dx];
                const f32x2 wq2 = {wqv, wqv}, wk2 = {wkv, wkv}, wv2 = {wvv, wvv};
                aq[yy][0] = __builtin_elementwise_fma(xa, wq2, aq[yy][0]);
                aq[yy][1] = __builtin_elementwise_fma(xb, wq2, aq[yy][1]);
                ak[yy][0] = __builtin_elementwise_fma(xa, wk2, ak[yy][0]);
                ak[yy][1] = __builtin_elementwise_fma(xb, wk2, ak[yy][1]);
                av[yy][0] = __builtin_elementwise_fma(xa, wv2, av[yy][0]);
                av[yy][1] = __builtin_elementwise_fma(xb, wv2, av[yy][1]);
            }
        }
    }

    // bf16 [bh][c][t]: hd = y>>4, t = (y&15)*128 + x
    #pragma unroll
    for (int yy = 0; yy < 4; ++yy) {
        const int y = ty0 + oy0 + yy;
        const size_t off = ((size_t)(b * 8 + (y >> 4)) * CH + c) * DHEAD
                         + (size_t)(y & 15) * WW + tx0 + x0;
        bf16x4v hq, hk, hv;
        hq[0] = (short)f2bf(aq[yy][0][0]); hq[1] = (short)f2bf(aq[yy][0][1]);
        hq[2] = (short)f2bf(aq[yy][1][0]); hq[3] = (short)f2bf(aq[yy][1][1]);
        hk[0] = (short)f2bf(ak[yy][0][0]); hk[1] = (short)f2bf(ak[yy][0][1]);
        hk[2] = (short)f2bf(ak[yy][1][0]); hk[3] = (short)f2bf(ak[yy][1][1]);
        hv[0] = (short)f2bf(av[yy][0][0]); hv[1] = (short)f2bf(av[yy][0][1]);
        hv[2] = (short)f2bf(av[yy][1][0]); hv[3] = (short)f2bf(av[yy][1][1]);
        *(bf16x4v*)&Qb[off] = hq;
        *(bf16x4v*)&Kb[off] = hk;
        *(bf16x4v*)&Vb[off] = hv;
    }
}

// ---------------- Kernel 2: Spart[split][bh] = Q_chunk K_chunk^T via MFMA ------
__global__ __launch_bounds__(256) void qk_mfma_kernel(
    const unsigned short* __restrict__ Qb, const unsigned short* __restrict__ Kb,
    float* __restrict__ Spart)
{
    const int blk   = blockIdx.x;
    const int split = blk & 7;
    const int bh    = blk >> 3;
    const int t0    = split * 256;

    __shared__ unsigned short Qs[128][72];
    __shared__ unsigned short Ks[128][72];

    const int tid  = threadIdx.x;
    const int wave = tid >> 6;
    const int lane = tid & 63;
    const int lx   = lane & 15;
    const int qd   = lane >> 4;
    const int m0   = (wave & 1) * 64;
    const int n0   = (wave >> 1) * 64;

    f32x4 acc[4][4];
    #pragma unroll
    for (int mi = 0; mi < 4; ++mi)
        #pragma unroll
        for (int ni = 0; ni < 4; ++ni) acc[mi][ni] = (f32x4){0.f, 0.f, 0.f, 0.f};

    const unsigned short* Qp = Qb + (size_t)bh * CH * DHEAD;
    const unsigned short* Kp = Kb + (size_t)bh * CH * DHEAD;

    #pragma unroll 1
    for (int tc = 0; tc < 256; tc += 64) {
        __syncthreads();
        for (int i = tid; i < 1024; i += 256) {
            const int r  = i >> 3;
            const int cl = (i & 7) << 3;
            *(bf16x8*)&Qs[r][cl] = *(const bf16x8*)&Qp[(size_t)r * DHEAD + t0 + tc + cl];
            *(bf16x8*)&Ks[r][cl] = *(const bf16x8*)&Kp[(size_t)r * DHEAD + t0 + tc + cl];
        }
        __syncthreads();
        #pragma unroll
        for (int ki = 0; ki < 2; ++ki) {
            const int kc = ki * 32 + qd * 8;
            bf16x8 a[4], bv[4];
            #pragma unroll
            for (int mi = 0; mi < 4; ++mi)
                a[mi] = *(const bf16x8*)&Qs[m0 + mi * 16 + lx][kc];
            #pragma unroll
            for (int ni = 0; ni < 4; ++ni)
                bv[ni] = *(const bf16x8*)&Ks[n0 + ni * 16 + lx][kc];
            #pragma unroll
            for (int mi = 0; mi < 4; ++mi)
                #pragma unroll
                for (int ni = 0; ni < 4; ++ni)
                    acc[mi][ni] = __builtin_amdgcn_mfma_f32_16x16x32_bf16(
                        a[mi], bv[ni], acc[mi][ni], 0, 0, 0);
        }
    }
    float* Sp = Spart + ((size_t)split * 64 + bh) * (CH * CH);
    #pragma unroll
    for (int mi = 0; mi < 4; ++mi)
        #pragma unroll
        for (int r = 0; r < 4; ++r) {
            const int c = m0 + mi * 16 + qd * 4 + r;
            #pragma unroll
            for (int ni = 0; ni < 4; ++ni)
                Sp[c * CH + n0 + ni * 16 + lx] = acc[mi][ni][r];
        }
}

// ---------------- Kernel 3: reduce 8 partials + row softmax -> P bf16 [c][e] ---
__global__ __launch_bounds__(256) void softmax_kernel(
    const float* __restrict__ Spart, unsigned short* __restrict__ Pb)
{
    const int row  = blockIdx.x * 4 + (threadIdx.x >> 6);   // bh*128 + c
    const int lane = threadIdx.x & 63;
    float v0 = 0.f, v1 = 0.f;
    #pragma unroll
    for (int s = 0; s < 8; ++s) {
        const float* Sp = Spart + (size_t)s * 64 * CH * CH + (size_t)row * CH;
        v0 += Sp[lane];
        v1 += Sp[lane + 64];
    }
    v0 *= 0.0078125f; v1 *= 0.0078125f;
    float m = fmaxf(v0, v1);
    #pragma unroll
    for (int off = 32; off > 0; off >>= 1) m = fmaxf(m, __shfl_down(m, off));
    m = __shfl(m, 0);
    const float e0 = __expf(v0 - m);
    const float e1 = __expf(v1 - m);
    float s = e0 + e1;
    #pragma unroll
    for (int off = 32; off > 0; off >>= 1) s += __shfl_down(s, off);
    s = __shfl(s, 0);
    const float inv = 1.f / s;
    Pb[(size_t)row * CH + lane]      = f2bf(e0 * inv);
    Pb[(size_t)row * CH + lane + 64] = f2bf(e1 * inv);
}

// ---------------- Kernel 4: A = P V via MFMA, out At[b][p][ci] bf16 ------------
__global__ __launch_bounds__(256) void pv_mfma_kernel(
    const unsigned short* __restrict__ Pb, const unsigned short* __restrict__ Vb,
    unsigned short* __restrict__ At)
{
    const int blk = blockIdx.x;
    const int t0  = (blk & 15) << 7;
    const int bh  = blk >> 4;

    __shared__ __align__(16) char smem[69632];
    unsigned short (*Ps)[136] = (unsigned short(*)[136])smem;            // 34816 B
    unsigned short (*Vs)[136] = (unsigned short(*)[136])(smem + 34816);  // 34816 B
    float (*So)[132] = (float(*)[132])smem;                              // reused

    const int tid  = threadIdx.x;
    const int wave = tid >> 6;
    const int lane = tid & 63;
    const int lx   = lane & 15;
    const int qd   = lane >> 4;
    const int m0   = (wave & 1) * 64;      // c tile
    const int n0   = (wave >> 1) * 64;     // t tile

    const unsigned short* Pp = Pb + (size_t)bh * CH * CH;
    const unsigned short* Vp = Vb + (size_t)bh * CH * DHEAD;

    for (int i = tid; i < 2048; i += 256) {
        const int r  = i >> 4;
        const int cl = (i & 15) << 3;
        *(bf16x8*)&Ps[r][cl] = *(const bf16x8*)&Pp[(size_t)r * CH + cl];
    }
    for (int i = tid; i < 2048; i += 256) {
        const int e   = i & 127;
        const int tc8 = (i >> 7) << 3;
        const bf16x8 vv = *(const bf16x8*)&Vp[(size_t)e * DHEAD + t0 + tc8];
        #pragma unroll
        for (int j = 0; j < 8; ++j) Vs[tc8 + j][e] = (unsigned short)vv[j];
    }
    __syncthreads();

    f32x4 acc[4][4];
    #pragma unroll
    for (int mi = 0; mi < 4; ++mi)
        #pragma unroll
        for (int ni = 0; ni < 4; ++ni) acc[mi][ni] = (f32x4){0.f, 0.f, 0.f, 0.f};

    #pragma unroll
    for (int ki = 0; ki < 4; ++ki) {
        const int kc = ki * 32 + qd * 8;
        bf16x8 a[4], bv[4];
        #pragma unroll
        for (int mi = 0; mi < 4; ++mi)
            a[mi] = *(const bf16x8*)&Ps[m0 + mi * 16 + lx][kc];
        #pragma unroll
        for (int ni = 0; ni < 4; ++ni)
            bv[ni] = *(const bf16x8*)&Vs[n0 + ni * 16 + lx][kc];
        #pragma unroll
        for (int mi = 0; mi < 4; ++mi)
            #pragma unroll
            for (int ni = 0; ni < 4; ++ni)
                acc[mi][ni] = __builtin_amdgcn_mfma_f32_16x16x32_bf16(
                    a[mi], bv[ni], acc[mi][ni], 0, 0, 0);
    }

    __syncthreads();
    #pragma unroll
    for (int mi = 0; mi < 4; ++mi)
        #pragma unroll
        for (int ni = 0; ni < 4; ++ni)
            #pragma unroll
            for (int r = 0; r < 4; ++r)
                So[n0 + ni * 16 + lx][m0 + mi * 16 + qd * 4 + r] = acc[mi][ni][r];
    __syncthreads();

    const int t  = tid >> 1;
    const int ch = (tid & 1) * 64;
    const size_t orow = (((size_t)(bh >> 3) * HWSZ) + (size_t)(bh & 7) * DHEAD + t0 + t) * CH + ch;
    #pragma unroll
    for (int j = 0; j < 8; ++j) {
        const float4 f0 = *(const float4*)&So[t][ch + j * 8];
        const float4 f1 = *(const float4*)&So[t][ch + j * 8 + 4];
        bf16x8 h;
        h[0] = (short)f2bf(f0.x); h[1] = (short)f2bf(f0.y);
        h[2] = (short)f2bf(f0.z); h[3] = (short)f2bf(f0.w);
        h[4] = (short)f2bf(f1.x); h[5] = (short)f2bf(f1.y);
        h[6] = (short)f2bf(f1.z); h[7] = (short)f2bf(f1.w);
        *(bf16x8*)&At[orow + j * 8] = h;
    }
}

// ---------------- Kernel 5a: weight prep wo fp32 -> Wt[tap][co][ci] bf16 ------
__global__ __launch_bounds__(256) void wprep_kernel(
    const float* __restrict__ wo, unsigned short* __restrict__ Wt)
{
    const int i = blockIdx.x * 256 + threadIdx.x;     // 9*128*128 = 147456
    const int tap = i >> 14;
    const int rem = i & 16383;
    const int co  = rem >> 7;
    const int ci  = rem & 127;
    Wt[i] = f2bf(wo[(size_t)(co * CH + ci) * 9 + tap]);
}

// ---------------- Kernel 5b: 3x3 dense conv via bf16 MFMA implicit GEMM -------
__global__ __launch_bounds__(256, 3) void conv3x3_mfma_kernel(
    const unsigned short* __restrict__ At, const unsigned short* __restrict__ Wt,
    const float* __restrict__ bo, float* __restrict__ out)
{
    const int blk = blockIdx.x;
    const int y   = blk & (HH - 1);
    const int b   = blk >> 7;

    __shared__ unsigned short sA[130][136];   // x in -1..128 (+1 offset)
    __shared__ unsigned short sW[128][72];

    const int tid  = threadIdx.x;
    const int wave = tid >> 6;
    const int lane = tid & 63;
    const int lx   = lane & 15;
    const int qd   = lane >> 4;
    const int m0   = (wave & 1) * 64;
    const int n0   = (wave >> 1) * 64;

    for (int i = tid; i < 272; i += 256) {
        const int r   = (i < 136) ? 0 : 129;
        const int col = (i < 136) ? i : (i - 136);
        sA[r][col] = 0;
    }

    f32x4 acc[4][4];
    #pragma unroll
    for (int mi = 0; mi < 4; ++mi) {
        f32x4 bv;
        #pragma unroll
        for (int r = 0; r < 4; ++r) bv[r] = bo[m0 + mi * 16 + qd * 4 + r];
        #pragma unroll
        for (int ni = 0; ni < 4; ++ni) acc[mi][ni] = bv;
    }

    const size_t abase = (size_t)b * HWSZ * CH;

    for (int dy = 0; dy < 3; ++dy) {
        const int gy = y + dy - 1;
        __syncthreads();
        if ((unsigned)gy < HH) {
            const unsigned short* row = At + abase + (size_t)gy * WW * CH;
            for (int i = tid; i < 2048; i += 256) {
                const int xx  = i >> 4;
                const int cc8 = (i & 15) << 3;
                *(float4*)&sA[xx + 1][cc8] = *(const float4*)&row[xx * CH + cc8];
            }
        } else {
            const float4 z = make_float4(0.f, 0.f, 0.f, 0.f);
            for (int i = tid; i < 2048; i += 256) {
                const int xx  = i >> 4;
                const int cc8 = (i & 15) << 3;
                *(float4*)&sA[xx + 1][cc8] = z;
            }
        }
        for (int dx = 0; dx < 3; ++dx) {
            const int tap = dy * 3 + dx;
            #pragma unroll 1
            for (int kh = 0; kh < 2; ++kh) {
                if (dx | kh) __syncthreads();
                const unsigned short* wt = Wt + (size_t)tap * CH * CH + kh * 64;
                for (int i = tid; i < 1024; i += 256) {
                    const int co  = i >> 3;
                    const int cc8 = (i & 7) << 3;
                    *(float4*)&sW[co][cc8] = *(const float4*)&wt[co * CH + cc8];
                }
                __syncthreads();
                #pragma unroll
                for (int ks = 0; ks < 2; ++ks) {
                    const int kc  = ks * 32 + qd * 8;
                    const int kca = kh * 64 + kc;
                    bf16x8 a[4], bfr[4];
                    #pragma unroll
                    for (int mi = 0; mi < 4; ++mi)
                        a[mi] = *(const bf16x8*)&sW[m0 + mi * 16 + lx][kc];
                    #pragma unroll
                    for (int ni = 0; ni < 4; ++ni)
                        bfr[ni] = *(const bf16x8*)&sA[n0 + ni * 16 + lx + dx][kca];
                    #pragma unroll
                    for (int mi = 0; mi < 4; ++mi)
                        #pragma unroll
                        for (int ni = 0; ni < 4; ++ni)
                            acc[mi][ni] = __builtin_amdgcn_mfma_f32_16x16x32_bf16(
                                a[mi], bfr[ni], acc[mi][ni], 0, 0, 0);
                }
            }
        }
    }

    const size_t obase = (size_t)b * CH * HWSZ + (size_t)y * WW;
    #pragma unroll
    for (int mi = 0; mi < 4; ++mi) {
        #pragma unroll
        for (int r = 0; r < 4; ++r) {
            const int co = m0 + mi * 16 + qd * 4 + r;
            float* orow = out + obase + (size_t)co * HWSZ;
            #pragma unroll
            for (int ni = 0; ni < 4; ++ni)
                orow[n0 + ni * 16 + lx] = acc[mi][ni][r];
        }
    }
}

extern "C" void kernel_launch(void* const* d_in, const int* in_sizes, int n_in,
                              void* d_out, int out_size, void* d_ws, size_t ws_size,
                              hipStream_t stream)
{
    const float* x  = (const float*)d_in[0];
    const float* wq = (const float*)d_in[1];
    const float* bq = (const float*)d_in[2];
    const float* wk = (const float*)d_in[3];
    const float* bk = (const float*)d_in[4];
    const float* wv = (const float*)d_in[5];
    const float* bv = (const float*)d_in[6];
    const float* wo = (const float*)d_in[7];
    const float* bo = (const float*)d_in[8];

    char* ws = (char*)d_ws;
    unsigned short* Qb    = (unsigned short*)(ws);                        // 32 MiB
    unsigned short* Kb    = (unsigned short*)(ws + (size_t)33554432);     // 32 MiB
    unsigned short* Vb    = (unsigned short*)(ws + (size_t)67108864);     // 32 MiB
    float*          Spart = (float*)        (ws + (size_t)100663296);     // 32 MiB
    unsigned short* Pb    = (unsigned short*)(ws + (size_t)134217728);    // 2 MiB
    unsigned short* At    = (unsigned short*)(ws + (size_t)136314880);    // 32 MiB -> ends 169869312
    unsigned short* Wt    = (unsigned short*)(ws + (size_t)169869312);    // 288 KiB

    dwconv_qkv_kernel<<<BATCH * CH * 4, 256, 0, stream>>>(x, wq, bq, wk, bk, wv, bv, Qb, Kb, Vb);
    wprep_kernel<<<576, 256, 0, stream>>>(wo, Wt);
    qk_mfma_kernel<<<64 * 8, 256, 0, stream>>>(Qb, Kb, Spart);
    softmax_kernel<<<2048, 256, 0, stream>>>(Spart, Pb);
    pv_mfma_kernel<<<64 * 16, 256, 0, stream>>>(Pb, Vb, At);
    conv3x3_mfma_kernel<<<BATCH * HH, 256, 0, stream>>>(At, Wt, bo, (float*)d_out);
}